// Round 11
// baseline (773.985 us; speedup 1.0000x reference)
//
#include <hip/hip_runtime.h>
#include <math.h>

#define N_NODES 650
#define DIM     512
#define E_RAW   150000
#define E_TOT   150650
#define NB      64
#define A_LD    768              // padded alpha row stride (4*192)
#define S_H     332800           // 650*512
#define GRID    512

__device__ __forceinline__ float4 ld4(const float* p) { return *(const float4*)p; }

// ---- grid barrier: all GRID blocks co-resident (2 blocks/CU x 256 CU) ----
__device__ __forceinline__ void gsync(unsigned* gbar, unsigned target) {
    __syncthreads();
    if (threadIdx.x == 0) {
        __threadfence();
        atomicAdd(gbar, 1u);
        volatile unsigned* vc = gbar;
        while (*vc < target) { }
    }
    __syncthreads();
    __threadfence();
}

// ---- 64x64-tile split-K GEMM unit: Pout[z] = Aload[:,zKC:] @ B[zKC:,:] ----
// mode 0: A plain [650][lda] (agg; B row guard gk<KbB)
// mode 1: concat rows<400 A0 else A1p (lda=512)
// mode 2: A = relu(Q0+Q1+Q2+Q3 + abias) (lda=512)
__device__ __attribute__((noinline))
void gemm_tile(int mode, const float* A0, const float* A1p,
               const float* abias, const float* B, float* Pout,
               int u, int KC, int KbB, int lda) {
    __shared__ float SA[32 * 68];
    __shared__ float SB[32 * 64];
    int t  = threadIdx.x;
    int tx = t & 15, ty = t >> 4;
    int col0 = (u & 7) * 64;
    int row0 = ((u >> 3) % 11) * 64;
    int z = u / 88;
    int kbase = z * KC;
    float acc[4][4] = {};
    int m = t >> 2, kq = (t & 3) * 4;
    int bkk = t >> 4, bn4 = (t & 15) * 4;

    for (int kb = kbase; kb < kbase + KC; kb += 32) {
        float4 va = make_float4(0.f, 0.f, 0.f, 0.f);
        float4 vb = va;
        int gr = row0 + m;
        if (gr < N_NODES) {
            if (mode == 1) {
                const float* rp = (gr < 400) ? (A0 + (size_t)gr * 512)
                                             : (A1p + (size_t)(gr - 400) * 512);
                va = ld4(rp + kb + kq);
                vb = ld4(rp + kb + kq + 16);
            } else if (mode == 2) {
                size_t base = (size_t)gr * 512 + kb + kq;
                float4 q0 = ld4(A0 + base);
                float4 q1 = ld4(A0 + (size_t)S_H + base);
                float4 q2 = ld4(A0 + 2 * (size_t)S_H + base);
                float4 q3 = ld4(A0 + 3 * (size_t)S_H + base);
                float4 bb = ld4(abias + kb + kq);
                va.x = fmaxf(q0.x + q1.x + q2.x + q3.x + bb.x, 0.f);
                va.y = fmaxf(q0.y + q1.y + q2.y + q3.y + bb.y, 0.f);
                va.z = fmaxf(q0.z + q1.z + q2.z + q3.z + bb.z, 0.f);
                va.w = fmaxf(q0.w + q1.w + q2.w + q3.w + bb.w, 0.f);
                q0 = ld4(A0 + base + 16);
                q1 = ld4(A0 + (size_t)S_H + base + 16);
                q2 = ld4(A0 + 2 * (size_t)S_H + base + 16);
                q3 = ld4(A0 + 3 * (size_t)S_H + base + 16);
                bb = ld4(abias + kb + kq + 16);
                vb.x = fmaxf(q0.x + q1.x + q2.x + q3.x + bb.x, 0.f);
                vb.y = fmaxf(q0.y + q1.y + q2.y + q3.y + bb.y, 0.f);
                vb.z = fmaxf(q0.z + q1.z + q2.z + q3.z + bb.z, 0.f);
                vb.w = fmaxf(q0.w + q1.w + q2.w + q3.w + bb.w, 0.f);
            } else {
                const float* rp = A0 + (size_t)gr * lda;
                va = ld4(rp + kb + kq);
                vb = ld4(rp + kb + kq + 16);
            }
        }
        SA[(kq + 0) * 68 + m] = va.x; SA[(kq + 1) * 68 + m] = va.y;
        SA[(kq + 2) * 68 + m] = va.z; SA[(kq + 3) * 68 + m] = va.w;
        SA[(kq + 16) * 68 + m] = vb.x; SA[(kq + 17) * 68 + m] = vb.y;
        SA[(kq + 18) * 68 + m] = vb.z; SA[(kq + 19) * 68 + m] = vb.w;
        {
            int gk0 = kb + bkk, gk1 = gk0 + 16;
            float4 zf = make_float4(0.f, 0.f, 0.f, 0.f);
            float4 v0 = (gk0 < KbB) ? ld4(&B[(size_t)gk0 * 512 + col0 + bn4]) : zf;
            float4 v1 = (gk1 < KbB) ? ld4(&B[(size_t)gk1 * 512 + col0 + bn4]) : zf;
            *(float4*)&SB[bkk * 64 + bn4] = v0;
            *(float4*)&SB[(bkk + 16) * 64 + bn4] = v1;
        }
        __syncthreads();
        #pragma unroll
        for (int kk = 0; kk < 32; kk++) {
            float4 av = *(const float4*)&SA[kk * 68 + ty * 4];
            float4 bv = *(const float4*)&SB[kk * 64 + tx * 4];
            acc[0][0] += av.x * bv.x; acc[0][1] += av.x * bv.y;
            acc[0][2] += av.x * bv.z; acc[0][3] += av.x * bv.w;
            acc[1][0] += av.y * bv.x; acc[1][1] += av.y * bv.y;
            acc[1][2] += av.y * bv.z; acc[1][3] += av.y * bv.w;
            acc[2][0] += av.z * bv.x; acc[2][1] += av.z * bv.y;
            acc[2][2] += av.z * bv.z; acc[2][3] += av.z * bv.w;
            acc[3][0] += av.w * bv.x; acc[3][1] += av.w * bv.y;
            acc[3][2] += av.w * bv.z; acc[3][3] += av.w * bv.w;
        }
        __syncthreads();
    }
    float* Pz = Pout + (size_t)z * S_H;
    #pragma unroll
    for (int i = 0; i < 4; i++) {
        int gr = row0 + ty * 4 + i;
        if (gr < N_NODES)
            *(float4*)&Pz[(size_t)gr * 512 + col0 + tx * 4] =
                make_float4(acc[i][0], acc[i][1], acc[i][2], acc[i][3]);
    }
}

__global__ __launch_bounds__(256, 2)
void mega(const float* __restrict__ x_s, const float* __restrict__ x_t,
          const int* __restrict__ ei,
          const float* __restrict__ W1, const float* __restrict__ asrc1,
          const float* __restrict__ adst1, const float* __restrict__ b1,
          const float* __restrict__ W4, const float* __restrict__ asrc4,
          const float* __restrict__ adst4, const float* __restrict__ b4,
          const float* __restrict__ fcw, const float* __restrict__ fcb,
          float* __restrict__ out, void* wsraw) {
    // ---- workspace layout ----
    unsigned* gbar = (unsigned*)wsraw;
    float* fp = (float*)wsraw + 4;
    float* P    = fp;  fp += 4 * (size_t)S_H;
    float* Q    = fp;  fp += 4 * (size_t)S_H;
    float* h1   = fp;  fp += S_H;
    float* h2   = fp;  fp += S_H;
    float* A1   = fp;  fp += (size_t)N_NODES * A_LD;
    float* A2   = fp;  fp += (size_t)N_NODES * A_LD;
    int* ip     = (int*)fp;
    int* ssrc   = ip;  ip += E_TOT;
    int* cntN   = ip;  ip += N_NODES * NB;     // node-major: cntN[n*NB+b]
    int* baseb  = ip;  ip += N_NODES * NB;     // node-major
    int* rowptr = ip;  ip += N_NODES + 1;
    float* als1 = (float*)ip;
    float* ald1 = als1 + N_NODES;
    float* als2 = ald1 + N_NODES;
    float* ald2 = als2 + N_NODES;
    float* ws2v = ald2 + N_NODES;
    float* wd2v = ws2v + 512;

    __shared__ int   iLC[N_NODES];    // hist / cursors / scan buffer
    __shared__ float fA[A_LD];        // alpha row accumulator
    __shared__ float redf[8];
    int t = threadIdx.x;
    int lane = t & 63, wv = t >> 6;
    const int per = (E_TOT + NB - 1) / NB;
    unsigned bar = 0;

    // ========== Phase 0: h1-gemm | edge count (node-major) | W4 matvecs ==========
    for (int u = blockIdx.x; u < 432; u += gridDim.x) {
        if (u < 352) {
            gemm_tile(1, x_s, x_t, nullptr, W1, P, u, 128, 512, 512);
        } else if (u < 416) {
            int cu = u - 352;
            __syncthreads();
            for (int n = t; n < N_NODES; n += 256) iLC[n] = 0;
            __syncthreads();
            int e0 = cu * per, e1 = min(e0 + per, E_TOT);
            for (int i = e0 + t; i < e1; i += 256) {
                int d = (i < E_RAW) ? ei[E_RAW + i] : i - E_RAW;
                atomicAdd(&iLC[d], 1);
            }
            __syncthreads();
            for (int n = t; n < N_NODES; n += 256) cntN[n * NB + cu] = iLC[n];
        } else {
            int mu = u - 416;
            const float* av = (mu >> 3) ? adst4 : asrc4;
            float* outv = (mu >> 3) ? wd2v : ws2v;
            int rg = mu & 7;
            for (int rr = 0; rr < 16; rr++) {
                int r = rg * 64 + rr * 4 + wv;
                float s = 0.f;
                for (int c = lane; c < 512; c += 64) s += W4[(size_t)r * 512 + c] * av[c];
                #pragma unroll
                for (int o = 32; o > 0; o >>= 1) s += __shfl_down(s, o);
                if (lane == 0) outv[r] = s;
            }
        }
    }
    bar += GRID; gsync(gbar, bar);

    // ===== Phase 1: h1 reduce + logits1 (650) | CSR scan+rowptr+baseb (1) =====
    for (int u = blockIdx.x; u < 651; u += gridDim.x) {
        __syncthreads();
        if (u < 650) {
            int r = u;
            size_t base = (size_t)r * 512;
            float v0 = P[base + t] + P[S_H + base + t] +
                       P[2 * (size_t)S_H + base + t] + P[3 * (size_t)S_H + base + t];
            float v1 = P[base + t + 256] + P[S_H + base + t + 256] +
                       P[2 * (size_t)S_H + base + t + 256] + P[3 * (size_t)S_H + base + t + 256];
            h1[base + t] = v0;
            h1[base + t + 256] = v1;
            float ps = v0 * asrc1[t] + v1 * asrc1[t + 256];
            float pd = v0 * adst1[t] + v1 * adst1[t + 256];
            #pragma unroll
            for (int o = 32; o > 0; o >>= 1) {
                ps += __shfl_down(ps, o);
                pd += __shfl_down(pd, o);
            }
            if (lane == 0) { redf[wv] = ps; redf[4 + wv] = pd; }
            __syncthreads();
            if (t == 0) als1[r] = redf[0] + redf[1] + redf[2] + redf[3];
            if (t == 1) ald1[r] = redf[4] + redf[5] + redf[6] + redf[7];
        } else {
            // thread t owns nodes 3t..3t+2 (consecutive) -> totals, LDS scan, bases
            int n0 = 3 * t;
            int tv[3]; int chunk = 0;
            #pragma unroll
            for (int j = 0; j < 3; j++) {
                int n = n0 + j; int s = 0;
                if (n < N_NODES) {
                    for (int b = 0; b < NB; b += 4) {
                        int4 c4 = *(const int4*)&cntN[n * NB + b];
                        s += c4.x + c4.y + c4.z + c4.w;
                    }
                }
                tv[j] = s; chunk += s;
            }
            iLC[t] = chunk;
            __syncthreads();
            for (int o = 1; o < 256; o <<= 1) {
                int x = (t >= o) ? iLC[t - o] : 0;
                __syncthreads();
                iLC[t] += x;
                __syncthreads();
            }
            int run = iLC[t] - chunk;     // exclusive prefix over threads
            #pragma unroll
            for (int j = 0; j < 3; j++) {
                int n = n0 + j;
                if (n < N_NODES) {
                    rowptr[n] = run;
                    for (int b = 0; b < NB; b++) {
                        baseb[n * NB + b] = run;
                        run += cntN[n * NB + b];
                    }
                }
            }
            if (t == 0) rowptr[N_NODES] = E_TOT;
        }
    }
    bar += GRID; gsync(gbar, bar);

    // ================= Phase 2: scatter (LDS cursors) =================
    for (int u = blockIdx.x; u < NB; u += gridDim.x) {
        __syncthreads();
        for (int n = t; n < N_NODES; n += 256) iLC[n] = baseb[n * NB + u];
        __syncthreads();
        int e0 = u * per, e1 = min(e0 + per, E_TOT);
        for (int i = e0 + t; i < e1; i += 256) {
            int s, d;
            if (i < E_RAW) { s = ei[i]; d = ei[E_RAW + i]; }
            else           { s = d = i - E_RAW; }
            int pos = atomicAdd(&iLC[d], 1);
            ssrc[pos] = s;
        }
    }
    bar += GRID; gsync(gbar, bar);

    // ================= Phase 3: alpha rows layer 1 =================
    for (int u = blockIdx.x; u < N_NODES; u += gridDim.x) {
        __syncthreads();
        for (int l = t; l < A_LD; l += 256) fA[l] = 0.f;
        __syncthreads();
        int r0 = rowptr[u], r1 = rowptr[u + 1];
        float aldd = ald1[u];
        float psum = 0.f;
        for (int l = r0 + t; l < r1; l += 256) {
            int s = ssrc[l];
            float v = als1[s] + aldd;
            v = v > 0.f ? v : 0.2f * v;
            float ex = __expf(v);
            atomicAdd(&fA[s], ex);
            psum += ex;
        }
        #pragma unroll
        for (int o = 32; o > 0; o >>= 1) psum += __shfl_down(psum, o);
        if (lane == 0) redf[wv] = psum;
        __syncthreads();
        float inv = 1.f / (redf[0] + redf[1] + redf[2] + redf[3] + 1e-16f);
        for (int q = t; q < A_LD / 4; q += 256) {
            float4 v = *(const float4*)&fA[q * 4];
            v.x *= inv; v.y *= inv; v.z *= inv; v.w *= inv;
            *(float4*)&A1[(size_t)u * A_LD + q * 4] = v;
        }
    }
    bar += GRID; gsync(gbar, bar);

    // ================= Phase 4: agg1 = A1 @ h1 -> Q partials =================
    for (int u = blockIdx.x; u < 352; u += gridDim.x)
        gemm_tile(0, A1, nullptr, nullptr, h1, Q, u, 192, N_NODES, A_LD);
    bar += GRID; gsync(gbar, bar);

    // ====== Phase 5: h2 = relu(o1)@W4 -> P partials | logits2 = o1 . ws2v ======
    for (int u = blockIdx.x; u < 1002; u += gridDim.x) {
        if (u < 352) {
            gemm_tile(2, Q, nullptr, b1, W4, P, u, 128, 512, 512);
        } else {
            int r = u - 352;
            __syncthreads();
            size_t base = (size_t)r * 512;
            float ps = 0.f, pd = 0.f;
            for (int k = t; k < 512; k += 256) {
                float v = Q[base + k] + Q[S_H + base + k] +
                          Q[2 * (size_t)S_H + base + k] + Q[3 * (size_t)S_H + base + k] + b1[k];
                v = fmaxf(v, 0.f);
                ps += v * ws2v[k];
                pd += v * wd2v[k];
            }
            #pragma unroll
            for (int o = 32; o > 0; o >>= 1) {
                ps += __shfl_down(ps, o);
                pd += __shfl_down(pd, o);
            }
            if (lane == 0) { redf[wv] = ps; redf[4 + wv] = pd; }
            __syncthreads();
            if (t == 0) als2[r] = redf[0] + redf[1] + redf[2] + redf[3];
            if (t == 1) ald2[r] = redf[4] + redf[5] + redf[6] + redf[7];
        }
    }
    bar += GRID; gsync(gbar, bar);

    // ============ Phase 6: h2 reduce (650) | alpha rows layer 2 (650) ============
    for (int u = blockIdx.x; u < 1300; u += gridDim.x) {
        __syncthreads();
        if (u < 650) {
            size_t base = (size_t)u * 512;
            float v0 = P[base + t] + P[S_H + base + t] +
                       P[2 * (size_t)S_H + base + t] + P[3 * (size_t)S_H + base + t];
            float v1 = P[base + t + 256] + P[S_H + base + t + 256] +
                       P[2 * (size_t)S_H + base + t + 256] + P[3 * (size_t)S_H + base + t + 256];
            h2[base + t] = v0;
            h2[base + t + 256] = v1;
        } else {
            int d = u - 650;
            for (int l = t; l < A_LD; l += 256) fA[l] = 0.f;
            __syncthreads();
            int r0 = rowptr[d], r1 = rowptr[d + 1];
            float aldd = ald2[d];
            float psum = 0.f;
            for (int l = r0 + t; l < r1; l += 256) {
                int s = ssrc[l];
                float v = als2[s] + aldd;
                v = v > 0.f ? v : 0.2f * v;
                float ex = __expf(v);
                atomicAdd(&fA[s], ex);
                psum += ex;
            }
            #pragma unroll
            for (int o = 32; o > 0; o >>= 1) psum += __shfl_down(psum, o);
            if (lane == 0) redf[wv] = psum;
            __syncthreads();
            float inv = 1.f / (redf[0] + redf[1] + redf[2] + redf[3] + 1e-16f);
            for (int q = t; q < A_LD / 4; q += 256) {
                float4 v = *(const float4*)&fA[q * 4];
                v.x *= inv; v.y *= inv; v.z *= inv; v.w *= inv;
                *(float4*)&A2[(size_t)d * A_LD + q * 4] = v;
            }
        }
    }
    bar += GRID; gsync(gbar, bar);

    // ================= Phase 7: agg2 = A2 @ h2 -> Q partials =================
    for (int u = blockIdx.x; u < 352; u += gridDim.x)
        gemm_tile(0, A2, nullptr, nullptr, h2, Q, u, 192, N_NODES, A_LD);
    bar += GRID; gsync(gbar, bar);

    // ================= Phase 8: final fc + sigmoid =================
    for (int u = blockIdx.x; u < 512; u += gridDim.x) {
        __syncthreads();
        float s = 0.f;
        for (int i = t; i < N_NODES; i += 256) {
            int g = u * N_NODES + i;
            float v = Q[g] + Q[S_H + g] + Q[2 * (size_t)S_H + g] +
                      Q[3 * (size_t)S_H + g] + b4[g & 511];
            v = v > 0.f ? v : 0.01f * v;
            s += v * fcw[i];
        }
        #pragma unroll
        for (int o = 32; o > 0; o >>= 1) s += __shfl_down(s, o);
        if (lane == 0) redf[wv] = s;
        __syncthreads();
        if (t == 0) {
            float tot = redf[0] + redf[1] + redf[2] + redf[3];
            out[u] = 1.f / (1.f + expf(-(tot + fcb[0])));
        }
    }
}

extern "C" void kernel_launch(void* const* d_in, const int* in_sizes, int n_in,
                              void* d_out, int out_size, void* d_ws, size_t ws_size,
                              hipStream_t stream) {
    const float* x_s   = (const float*)d_in[0];
    const float* x_t   = (const float*)d_in[1];
    const int*   ei    = (const int*)d_in[2];
    const float* W1    = (const float*)d_in[5];
    const float* asrc1 = (const float*)d_in[6];
    const float* adst1 = (const float*)d_in[7];
    const float* b1    = (const float*)d_in[8];
    const float* W4    = (const float*)d_in[9];
    const float* asrc4 = (const float*)d_in[10];
    const float* adst4 = (const float*)d_in[11];
    const float* b4    = (const float*)d_in[12];
    const float* fcw   = (const float*)d_in[13];
    const float* fcb   = (const float*)d_in[14];
    float* out = (float*)d_out;

    // zero the grid-barrier counter
    hipMemsetAsync(d_ws, 0, 16, stream);

    mega<<<dim3(GRID), dim3(256), 0, stream>>>(
        x_s, x_t, ei, W1, asrc1, adst1, b1,
        W4, asrc4, adst4, b4, fcw, fcb, out, d_ws);
}